// Round 2
// baseline (899.321 us; speedup 1.0000x reference)
//
#include <hip/hip_runtime.h>

constexpr int F  = 32;
constexpr int V  = 10000;
constexpr int D  = 496;     // 124 float4 chunks: lane l owns chunks l and 64+l (l<60)
constexpr int H  = 1024;

// ---------------- Kernel 1: FM interaction (gather-heavy) -----------------
// 4 batch rows per 256-thread block, ONE WAVE PER ROW. After a single staging
// barrier each wave is fully independent: no cross-wave reduction, no block
// barrier in the hot loop. Lane l reads float4 chunks l and 64+l of each
// gathered row; lanes 60..63 read a clamped duplicate (valid address) and
// their second-chunk contribution is masked out at the end -> divergence-free
// hot loop. unroll 4 keeps ~8 dwordx4 gathers in flight per wave.
__global__ __launch_bounds__(256, 6) void fm_kernel(
    const float* __restrict__ xv,   // [B,F]
    const int*   __restrict__ xi,   // [B,F]
    const float* __restrict__ emb,  // [F,V,D]
    const float* __restrict__ W2,   // [D+H,1]
    const float* __restrict__ b2,   // [1]
    float* __restrict__ out,        // [B]
    int B)
{
    const int t  = threadIdx.x;
    const int w  = t >> 6;          // wave id 0..3  -> batch row b0+w
    const int l  = t & 63;          // lane
    const int b0 = blockIdx.x * 4;

    __shared__ float        s_xv[4][F];
    __shared__ const float* s_row[4][F];

    if (t < 128) {
        const int rr = t >> 5, f = t & 31;
        const int r  = min(b0 + rr, B - 1);
        s_xv[rr][f]  = xv[(size_t)r * F + f];
        s_row[rr][f] = emb + ((size_t)f * V + (size_t)xi[(size_t)r * F + f]) * D;
    }
    __syncthreads();

    const int   c1 = (l < 60) ? l : 59;       // clamped second-chunk id
    const float m1 = (l < 60) ? 1.0f : 0.0f;  // mask for duplicate lanes

    float4 s0  = make_float4(0.f, 0.f, 0.f, 0.f);
    float4 ss0 = make_float4(0.f, 0.f, 0.f, 0.f);
    float4 s1  = make_float4(0.f, 0.f, 0.f, 0.f);
    float4 ss1 = make_float4(0.f, 0.f, 0.f, 0.f);

    #pragma unroll 4
    for (int f = 0; f < F; ++f) {
        const float  xf = s_xv[w][f];
        const float* p  = s_row[w][f];
        float4 v0 = *reinterpret_cast<const float4*>(p + 4 * l);
        float4 v1 = *reinterpret_cast<const float4*>(p + 256 + 4 * c1);
        v0.x *= xf; v0.y *= xf; v0.z *= xf; v0.w *= xf;
        v1.x *= xf; v1.y *= xf; v1.z *= xf; v1.w *= xf;
        s0.x  += v0.x;        s0.y  += v0.y;        s0.z  += v0.z;        s0.w  += v0.w;
        ss0.x += v0.x * v0.x; ss0.y += v0.y * v0.y; ss0.z += v0.z * v0.z; ss0.w += v0.w * v0.w;
        s1.x  += v1.x;        s1.y  += v1.y;        s1.z  += v1.z;        s1.w  += v1.w;
        ss1.x += v1.x * v1.x; ss1.y += v1.y * v1.y; ss1.z += v1.z * v1.z; ss1.w += v1.w * v1.w;
    }

    const float4 w2a = *reinterpret_cast<const float4*>(W2 + 4 * l);
    const float4 w2b = *reinterpret_cast<const float4*>(W2 + 256 + 4 * c1);

    float acc = (0.5f * (s0.x * s0.x - ss0.x)) * w2a.x
              + (0.5f * (s0.y * s0.y - ss0.y)) * w2a.y
              + (0.5f * (s0.z * s0.z - ss0.z)) * w2a.z
              + (0.5f * (s0.w * s0.w - ss0.w)) * w2a.w
        + m1 * ((0.5f * (s1.x * s1.x - ss1.x)) * w2b.x
              + (0.5f * (s1.y * s1.y - ss1.y)) * w2b.y
              + (0.5f * (s1.z * s1.z - ss1.z)) * w2b.z
              + (0.5f * (s1.w * s1.w - ss1.w)) * w2b.w);

    #pragma unroll
    for (int off = 32; off > 0; off >>= 1)
        acc += __shfl_down(acc, off, 64);
    if (l == 0 && b0 + w < B) out[b0 + w] = acc + b2[0];
}

// ---------------- Kernel 2: MLP branch (unchanged from round 1) -----------
constexpr int R  = 64;   // rows per block
constexpr int RC = 8;    // row chunk held in registers

__global__ __launch_bounds__(256, 4) void mlp_kernel(
    const float* __restrict__ xv,   // [B,F]
    const float* __restrict__ W1,   // [F,H]
    const float* __restrict__ b1,   // [H]
    const float* __restrict__ W2,   // [D+H,1]
    float* __restrict__ out,        // [B] (accumulates onto fm_kernel output)
    int B)
{
    const int t  = threadIdx.x;
    const int b0 = blockIdx.x * R;
    const int j0 = 4 * t;           // H-column base, 256*4 = 1024 = H

    __shared__ float s_xv[F][R];    // transposed tile: [field][row], 8 KB
    __shared__ float s_red[RC][4];

    {
        const int r0 = t >> 3, f0 = 4 * (t & 7);
        const int rA = min(b0 + r0,      B - 1);
        const int rB = min(b0 + r0 + 32, B - 1);
        float4 v0 = *reinterpret_cast<const float4*>(xv + (size_t)rA * F + f0);
        float4 v1 = *reinterpret_cast<const float4*>(xv + (size_t)rB * F + f0);
        s_xv[f0 + 0][r0] = v0.x; s_xv[f0 + 1][r0] = v0.y;
        s_xv[f0 + 2][r0] = v0.z; s_xv[f0 + 3][r0] = v0.w;
        s_xv[f0 + 0][r0 + 32] = v1.x; s_xv[f0 + 1][r0 + 32] = v1.y;
        s_xv[f0 + 2][r0 + 32] = v1.z; s_xv[f0 + 3][r0 + 32] = v1.w;
    }
    __syncthreads();

    const float4 w2v = *reinterpret_cast<const float4*>(W2 + D + j0);
    const float4 bv  = *reinterpret_cast<const float4*>(b1 + j0);

    for (int rc = 0; rc < R; rc += RC) {
        float4 h[RC];
        #pragma unroll
        for (int r = 0; r < RC; ++r) h[r] = bv;

        #pragma unroll 4
        for (int f = 0; f < F; ++f) {
            const float4 w  = *reinterpret_cast<const float4*>(W1 + f * H + j0);
            const float4 xa = *reinterpret_cast<const float4*>(&s_xv[f][rc]);
            const float4 xb = *reinterpret_cast<const float4*>(&s_xv[f][rc + 4]);
            const float xr[RC] = {xa.x, xa.y, xa.z, xa.w, xb.x, xb.y, xb.z, xb.w};
            #pragma unroll
            for (int r = 0; r < RC; ++r) {
                h[r].x += xr[r] * w.x; h[r].y += xr[r] * w.y;
                h[r].z += xr[r] * w.z; h[r].w += xr[r] * w.w;
            }
        }

        #pragma unroll
        for (int r = 0; r < RC; ++r) {
            float p = fmaxf(h[r].x, 0.f) * w2v.x + fmaxf(h[r].y, 0.f) * w2v.y
                    + fmaxf(h[r].z, 0.f) * w2v.z + fmaxf(h[r].w, 0.f) * w2v.w;
            #pragma unroll
            for (int off = 32; off > 0; off >>= 1)
                p += __shfl_down(p, off, 64);
            if ((t & 63) == 0) s_red[r][t >> 6] = p;
        }
        __syncthreads();
        if (t < RC) {
            const int row = b0 + rc + t;
            if (row < B)
                out[row] += s_red[t][0] + s_red[t][1] + s_red[t][2] + s_red[t][3];
        }
        __syncthreads();
    }
}

extern "C" void kernel_launch(void* const* d_in, const int* in_sizes, int n_in,
                              void* d_out, int out_size, void* d_ws, size_t ws_size,
                              hipStream_t stream) {
    const float* xv  = (const float*)d_in[0];
    const int*   xi  = (const int*)d_in[1];
    const float* emb = (const float*)d_in[2];
    const float* W1  = (const float*)d_in[3];
    const float* b1  = (const float*)d_in[4];
    const float* W2  = (const float*)d_in[5];
    const float* b2  = (const float*)d_in[6];
    float* out = (float*)d_out;

    const int B = in_sizes[0] / F;

    fm_kernel<<<(B + 3) / 4, 256, 0, stream>>>(xv, xi, emb, W2, b2, out, B);
    mlp_kernel<<<(B + R - 1) / R, 256, 0, stream>>>(xv, W1, b1, W2, out, B);
}

// Round 3
// 838.557 us; speedup vs baseline: 1.0725x; 1.0725x over previous
//
#include <hip/hip_runtime.h>

constexpr int F  = 32;
constexpr int V  = 10000;
constexpr int D  = 496;     // 124 float4 chunks
constexpr int H  = 1024;
constexpr int RM = 64;      // rows per MLP block
constexpr int RC = 8;       // row chunk held in registers (MLP)

// ---------------- Fused heterogeneous kernel --------------------------------
// Blocks [0, nMLP)           : MLP path, 64 rows each  -> ws[B + row]
// Blocks [nMLP, nMLP + nFM)  : FM  path, 4 rows each   -> ws[row]
// MLP blocks are FIRST in dispatch order so they co-schedule with the FM
// wave-front and their L2-bound W1 traffic hides under the FM HBM gather.
__global__ __launch_bounds__(256, 4) void deepqi_hetero(
    const float* __restrict__ xv,   // [B,F]
    const int*   __restrict__ xi,   // [B,F]
    const float* __restrict__ emb,  // [F,V,D]
    const float* __restrict__ W1,   // [F,H]
    const float* __restrict__ b1,   // [H]
    const float* __restrict__ W2,   // [D+H,1]
    float* __restrict__ ws,         // [2*B] scratch: [0,B)=FM part, [B,2B)=MLP part
    int B, int nMLP)
{
    const int t = threadIdx.x;

    if ((int)blockIdx.x < nMLP) {
        // ================= MLP path (round-1 verified structure) ===========
        const int b0 = blockIdx.x * RM;
        const int j0 = 4 * t;                 // H-column base, 256*4 = 1024 = H

        __shared__ float s_xv[F][RM];         // transposed tile, 8 KB
        __shared__ float s_red[RC][4];

        {
            const int r0 = t >> 3, f0 = 4 * (t & 7);
            const int rA = min(b0 + r0,      B - 1);
            const int rB = min(b0 + r0 + 32, B - 1);
            float4 v0 = *reinterpret_cast<const float4*>(xv + (size_t)rA * F + f0);
            float4 v1 = *reinterpret_cast<const float4*>(xv + (size_t)rB * F + f0);
            s_xv[f0 + 0][r0] = v0.x; s_xv[f0 + 1][r0] = v0.y;
            s_xv[f0 + 2][r0] = v0.z; s_xv[f0 + 3][r0] = v0.w;
            s_xv[f0 + 0][r0 + 32] = v1.x; s_xv[f0 + 1][r0 + 32] = v1.y;
            s_xv[f0 + 2][r0 + 32] = v1.z; s_xv[f0 + 3][r0 + 32] = v1.w;
        }
        __syncthreads();

        const float4 w2v = *reinterpret_cast<const float4*>(W2 + D + j0);
        const float4 bv  = *reinterpret_cast<const float4*>(b1 + j0);

        for (int rc = 0; rc < RM; rc += RC) {
            float4 h[RC];
            #pragma unroll
            for (int r = 0; r < RC; ++r) h[r] = bv;

            #pragma unroll 4
            for (int f = 0; f < F; ++f) {
                const float4 w  = *reinterpret_cast<const float4*>(W1 + f * H + j0);
                const float4 xa = *reinterpret_cast<const float4*>(&s_xv[f][rc]);
                const float4 xb = *reinterpret_cast<const float4*>(&s_xv[f][rc + 4]);
                const float xr[RC] = {xa.x, xa.y, xa.z, xa.w, xb.x, xb.y, xb.z, xb.w};
                #pragma unroll
                for (int r = 0; r < RC; ++r) {
                    h[r].x += xr[r] * w.x; h[r].y += xr[r] * w.y;
                    h[r].z += xr[r] * w.z; h[r].w += xr[r] * w.w;
                }
            }

            #pragma unroll
            for (int r = 0; r < RC; ++r) {
                float p = fmaxf(h[r].x, 0.f) * w2v.x + fmaxf(h[r].y, 0.f) * w2v.y
                        + fmaxf(h[r].z, 0.f) * w2v.z + fmaxf(h[r].w, 0.f) * w2v.w;
                #pragma unroll
                for (int off = 32; off > 0; off >>= 1)
                    p += __shfl_down(p, off, 64);
                if ((t & 63) == 0) s_red[r][t >> 6] = p;
            }
            __syncthreads();
            if (t < RC) {
                const int row = b0 + rc + t;
                if (row < B)
                    ws[(size_t)B + row] = s_red[t][0] + s_red[t][1] + s_red[t][2] + s_red[t][3];
            }
            __syncthreads();
        }
    } else {
        // ================= FM path (wave-per-row, divergence-free) =========
        const int w  = t >> 6;                 // wave id 0..3 -> batch row
        const int l  = t & 63;                 // lane
        const int b0 = ((int)blockIdx.x - nMLP) * 4;

        __shared__ float        s_xv2[4][F];
        __shared__ const float* s_row[4][F];

        if (t < 128) {
            const int rr = t >> 5, f = t & 31;
            const int r  = min(b0 + rr, B - 1);
            s_xv2[rr][f] = xv[(size_t)r * F + f];
            s_row[rr][f] = emb + ((size_t)f * V + (size_t)xi[(size_t)r * F + f]) * D;
        }
        __syncthreads();

        const int   c1 = (l < 60) ? l : 59;        // clamped second-chunk id
        const float m1 = (l < 60) ? 1.0f : 0.0f;   // mask for duplicate lanes

        float4 s0  = make_float4(0.f, 0.f, 0.f, 0.f);
        float4 ss0 = make_float4(0.f, 0.f, 0.f, 0.f);
        float4 s1  = make_float4(0.f, 0.f, 0.f, 0.f);
        float4 ss1 = make_float4(0.f, 0.f, 0.f, 0.f);

        #pragma unroll 4
        for (int f = 0; f < F; ++f) {
            const float  xf = s_xv2[w][f];
            const float* p  = s_row[w][f];
            float4 v0 = *reinterpret_cast<const float4*>(p + 4 * l);
            float4 v1 = *reinterpret_cast<const float4*>(p + 256 + 4 * c1);
            v0.x *= xf; v0.y *= xf; v0.z *= xf; v0.w *= xf;
            v1.x *= xf; v1.y *= xf; v1.z *= xf; v1.w *= xf;
            s0.x  += v0.x;        s0.y  += v0.y;        s0.z  += v0.z;        s0.w  += v0.w;
            ss0.x += v0.x * v0.x; ss0.y += v0.y * v0.y; ss0.z += v0.z * v0.z; ss0.w += v0.w * v0.w;
            s1.x  += v1.x;        s1.y  += v1.y;        s1.z  += v1.z;        s1.w  += v1.w;
            ss1.x += v1.x * v1.x; ss1.y += v1.y * v1.y; ss1.z += v1.z * v1.z; ss1.w += v1.w * v1.w;
        }

        const float4 w2a = *reinterpret_cast<const float4*>(W2 + 4 * l);
        const float4 w2b = *reinterpret_cast<const float4*>(W2 + 256 + 4 * c1);

        float acc = (0.5f * (s0.x * s0.x - ss0.x)) * w2a.x
                  + (0.5f * (s0.y * s0.y - ss0.y)) * w2a.y
                  + (0.5f * (s0.z * s0.z - ss0.z)) * w2a.z
                  + (0.5f * (s0.w * s0.w - ss0.w)) * w2a.w
            + m1 * ((0.5f * (s1.x * s1.x - ss1.x)) * w2b.x
                  + (0.5f * (s1.y * s1.y - ss1.y)) * w2b.y
                  + (0.5f * (s1.z * s1.z - ss1.z)) * w2b.z
                  + (0.5f * (s1.w * s1.w - ss1.w)) * w2b.w);

        #pragma unroll
        for (int off = 32; off > 0; off >>= 1)
            acc += __shfl_down(acc, off, 64);
        if (l == 0 && b0 + w < B) ws[b0 + w] = acc;
    }
}

// ---------------- Combine: out = fm + mlp + b2 ------------------------------
__global__ __launch_bounds__(256) void combine_kernel(
    const float* __restrict__ ws, const float* __restrict__ b2,
    float* __restrict__ out, int B)
{
    const int i = blockIdx.x * 256 + threadIdx.x;
    if (i < B) out[i] = ws[i] + ws[(size_t)B + i] + b2[0];
}

extern "C" void kernel_launch(void* const* d_in, const int* in_sizes, int n_in,
                              void* d_out, int out_size, void* d_ws, size_t ws_size,
                              hipStream_t stream) {
    const float* xv  = (const float*)d_in[0];
    const int*   xi  = (const int*)d_in[1];
    const float* emb = (const float*)d_in[2];
    const float* W1  = (const float*)d_in[3];
    const float* b1  = (const float*)d_in[4];
    const float* W2  = (const float*)d_in[5];
    const float* b2  = (const float*)d_in[6];
    float* out = (float*)d_out;
    float* ws  = (float*)d_ws;

    const int B    = in_sizes[0] / F;
    const int nMLP = (B + RM - 1) / RM;       // 256 blocks, dispatched first
    const int nFM  = (B + 3) / 4;             // 4096 blocks

    deepqi_hetero<<<nMLP + nFM, 256, 0, stream>>>(xv, xi, emb, W1, b1, W2, ws, B, nMLP);
    combine_kernel<<<(B + 255) / 256, 256, 0, stream>>>(ws, b2, out, B);
}